// Round 2
// baseline (8748.982 us; speedup 1.0000x reference)
//
#include <hip/hip_runtime.h>
#include <stdint.h>

#define Bd   128
#define Td   1000
#define INd  700
#define Hd   512
#define OUTd 20
#define Md   (Bd * Td)

// ---------------------------------------------------------------------------
// GEMM1: proj[m][n] = sum_k X[m][k] * W1[n][k] + b1[n]
// Tile 128m x 256n, BK=8, 256 threads, 8x16 micro-tile as split quads
// (rows {ty*4+i, 64+ty*4+i}, cols {c*64+tx*4+j}) -> all LDS reads <=2-way.
// Double-buffered LDS, one barrier per K-iter. Accumulation order over k is
// ascending fmaf chain per element == round-1 kernel -> proj bit-identical.
// ---------------------------------------------------------------------------
__global__ __launch_bounds__(256, 2) void gemm1_kernel(
    const float* __restrict__ X, const float* __restrict__ W1,
    const float* __restrict__ b1, float* __restrict__ proj) {
  __shared__ __align__(16) float As[2][8][128];
  __shared__ __align__(16) float Bs[2][8][256];
  const int tid = threadIdx.x;
  const int n0 = blockIdx.x * 256;   // n fastest in dispatch -> X L2 reuse
  const int m0 = blockIdx.y * 128;
  const int tx = tid & 15;           // n quad group
  const int ty = tid >> 4;           // m quad group
  const int arow = tid >> 1, acol = (tid & 1) << 2;

  const float* Ap = X + (size_t)(m0 + arow) * INd + acol;
  const float* Bp = W1 + (size_t)(n0 + tid) * INd;

  const float4 z4 = make_float4(0.f, 0.f, 0.f, 0.f);
  float4 ar, br0, br1;

  // prologue: tile 0 (k0=0, fully in-bounds)
  ar  = *(const float4*)(Ap);
  br0 = *(const float4*)(Bp);
  br1 = *(const float4*)(Bp + 4);
  {
    As[0][acol + 0][arow] = ar.x; As[0][acol + 1][arow] = ar.y;
    As[0][acol + 2][arow] = ar.z; As[0][acol + 3][arow] = ar.w;
    Bs[0][0][tid] = br0.x; Bs[0][1][tid] = br0.y;
    Bs[0][2][tid] = br0.z; Bs[0][3][tid] = br0.w;
    Bs[0][4][tid] = br1.x; Bs[0][5][tid] = br1.y;
    Bs[0][6][tid] = br1.z; Bs[0][7][tid] = br1.w;
  }
  __syncthreads();

  float acc[8][16];
#pragma unroll
  for (int i = 0; i < 8; ++i)
#pragma unroll
    for (int j = 0; j < 16; ++j) acc[i][j] = 0.f;

  const int KITERS = (INd + 7) / 8;  // 88; last iter half-valid (700 = 87*8+4)
#pragma unroll 1
  for (int iter = 0; iter < KITERS; ++iter) {
    const int cur = iter & 1;
    if (iter + 1 < KITERS) {
      const int k0 = (iter + 1) * 8;           // <= 696
      ar  = (k0 + acol < INd) ? *(const float4*)(Ap + k0) : z4;
      br0 = *(const float4*)(Bp + k0);          // k0 <= 696, always valid
      br1 = (k0 + 4 < INd) ? *(const float4*)(Bp + k0 + 4) : z4;
    }
#pragma unroll
    for (int k = 0; k < 8; ++k) {
      float a[8], b[16];
      *(float4*)&a[0] = *(const float4*)&As[cur][k][ty * 4];
      *(float4*)&a[4] = *(const float4*)&As[cur][k][64 + ty * 4];
#pragma unroll
      for (int c = 0; c < 4; ++c)
        *(float4*)&b[c * 4] = *(const float4*)&Bs[cur][k][c * 64 + tx * 4];
#pragma unroll
      for (int i = 0; i < 8; ++i)
#pragma unroll
        for (int j = 0; j < 16; ++j) acc[i][j] = fmaf(a[i], b[j], acc[i][j]);
    }
    if (iter + 1 < KITERS) {
      const int nxt = cur ^ 1;
      As[nxt][acol + 0][arow] = ar.x; As[nxt][acol + 1][arow] = ar.y;
      As[nxt][acol + 2][arow] = ar.z; As[nxt][acol + 3][arow] = ar.w;
      Bs[nxt][0][tid] = br0.x; Bs[nxt][1][tid] = br0.y;
      Bs[nxt][2][tid] = br0.z; Bs[nxt][3][tid] = br0.w;
      Bs[nxt][4][tid] = br1.x; Bs[nxt][5][tid] = br1.y;
      Bs[nxt][6][tid] = br1.z; Bs[nxt][7][tid] = br1.w;
      __syncthreads();
    }
  }

  float4 bq[4];
#pragma unroll
  for (int c = 0; c < 4; ++c)
    bq[c] = *(const float4*)&b1[n0 + c * 64 + tx * 4];

#pragma unroll
  for (int r = 0; r < 2; ++r)
#pragma unroll
    for (int i = 0; i < 4; ++i) {
      const int m = m0 + r * 64 + ty * 4 + i;
      float* row = proj + (size_t)m * Hd + n0;
#pragma unroll
      for (int c = 0; c < 4; ++c) {
        float4 v;
        v.x = acc[r * 4 + i][c * 4 + 0] + bq[c].x;
        v.y = acc[r * 4 + i][c * 4 + 1] + bq[c].y;
        v.z = acc[r * 4 + i][c * 4 + 2] + bq[c].z;
        v.w = acc[r * 4 + i][c * 4 + 3] + bq[c].w;
        *(float4*)(row + c * 64 + tx * 4) = v;
      }
    }
}

// ---------------------------------------------------------------------------
// Scan1: per-(b,h) LIF + dendritic filter; emit spike bitmasks.
// Only 1 wave/SIMD exists (65536 threads) -> latency-bound; 4-deep x 8-wide
// register prefetch ring keeps ~32 loads in flight per thread.
// Arithmetic expressions identical to the passing round-1 kernel.
// ---------------------------------------------------------------------------
__global__ __launch_bounds__(256) void scan1_kernel(
    const float* __restrict__ proj, const float* __restrict__ tau_m1,
    const float* __restrict__ tau_n1, const float* __restrict__ mem1_0,
    unsigned long long* __restrict__ spk) {
  const int gid = blockIdx.x * 256 + threadIdx.x;   // 0..65535
  const int b = gid >> 9;
  const int h = gid & 511;
  const float am = 1.f / (1.f + expf(-tau_m1[h]));
  const float bn = 1.f / (1.f + expf(-tau_n1[h]));
  const float omam = 1.f - am, ombn = 1.f - bn;
  float mem = mem1_0[(b << 9) | h];
  float d = 0.f, s = 0.f;
  const float* pp = proj + (size_t)b * Td * Hd + h;
  unsigned long long* sp = spk + (size_t)b * Td * 8 + (h >> 6);
  const int lane = threadIdx.x & 63;

  float buf[4][8];
#pragma unroll
  for (int q = 0; q < 3; ++q)
#pragma unroll
    for (int u = 0; u < 8; ++u)
      buf[q][u] = pp[(size_t)(q * 8 + u) * Hd];

#pragma unroll 1
  for (int t0 = 0; t0 < Td; t0 += 8) {
    const int qc = (t0 >> 3) & 3;
    const int qn = (qc + 3) & 3;      // slot 3 steps ahead
    const int tp = t0 + 24;
#pragma unroll
    for (int u = 0; u < 8; ++u) {
      const int tt = (tp + u < Td) ? (tp + u) : (Td - 1);
      buf[qn][u] = pp[(size_t)tt * Hd];
    }
#pragma unroll
    for (int u = 0; u < 8; ++u) {
      const float p = buf[qc][u];
      d = bn * d + ombn * p;
      mem = am * mem + omam * d - s;
      const bool fire = mem > 1.0f;
      s = fire ? 1.f : 0.f;
      const unsigned long long msk = __ballot(fire);
      if (lane == 0) sp[(size_t)(t0 + u) * 8] = msk;
    }
  }
}

// ---------------------------------------------------------------------------
// GEMM2: R[m][o] = b2[o] + sum over set spike bits h of W2[o][h].
// ---------------------------------------------------------------------------
__global__ __launch_bounds__(256) void gemm2_kernel(
    const unsigned long long* __restrict__ spk, const float* __restrict__ W2,
    const float* __restrict__ b2, float* __restrict__ R, int Mtotal) {
  __shared__ float W2s[Hd * OUTd];
  const int tid = threadIdx.x;
  for (int idx = tid; idx < Hd * OUTd; idx += 256) {
    const int h = idx / OUTd, o = idx - h * OUTd;
    W2s[idx] = W2[o * Hd + h];
  }
  __syncthreads();
  const int wave = tid >> 6, lane = tid & 63;
  const int mg = lane / OUTd;            // 0..3 (3 = idle lane)
  const int o = lane - mg * OUTd;        // 0..19
  if (mg >= 3) return;                   // no barriers after this point
  const float bias = b2[o];
  const int mbase = blockIdx.x * 96 + wave * 24 + mg;
#pragma unroll 1
  for (int i = 0; i < 8; ++i) {
    const int m = mbase + i * 3;
    if (m >= Mtotal) break;
    float r = bias;
    const unsigned long long* mp = spk + (size_t)m * 8;
#pragma unroll
    for (int c = 0; c < 8; ++c) {
      unsigned long long mask = mp[c];
      const float* wrow = W2s + (c << 6) * OUTd + o;
      while (mask) {
        const int j = __builtin_ctzll(mask);
        mask &= mask - 1;
        r += wrow[j * OUTd];
      }
    }
    R[(size_t)m * OUTd + o] = r;
  }
}

// ---------------------------------------------------------------------------
// Scan2: per-(b,o) leaky readout, chunked parallel scan.
// 8 chunks of 125 per (b,o); phase1 local sums, serial chunk-combine with
// a^125, phase2 emit. Post-spike + linear -> ~1e-6 reorder noise vs 1.9e-2
// threshold is irrelevant. 128 blocks x 160 active threads.
// ---------------------------------------------------------------------------
__global__ __launch_bounds__(256) void scan2_kernel(
    const float* __restrict__ R, const float* __restrict__ tau_m2,
    const float* __restrict__ mem2_0, float* __restrict__ out) {
  __shared__ float leS[8][20];
  __shared__ float stS[8][20];
  const int b = blockIdx.x;
  const int tid = threadIdx.x;
  const int c = tid / OUTd;          // chunk 0..7 (active if tid < 160)
  const int o = tid - c * OUTd;
  const bool active = tid < 160;
  float a2 = 0.f, oma2 = 0.f;
  if (active) {
    a2 = 1.f / (1.f + expf(-tau_m2[o]));
    oma2 = 1.f - a2;
  }
  const float* Rb = R + (size_t)b * Td * OUTd;
  float* Ob = out + (size_t)b * Td * OUTd;
  const int t0 = c * 125;

  if (active) {
    float m = 0.f;
    for (int u = 0; u < 125; ++u)
      m = a2 * m + oma2 * Rb[(size_t)(t0 + u) * OUTd + o];
    leS[c][o] = m;
  }
  __syncthreads();
  if (tid < OUTd) {
    const float a = 1.f / (1.f + expf(-tau_m2[tid]));
    float aL = 1.f;
    for (int i = 0; i < 125; ++i) aL *= a;
    float m = mem2_0[b * OUTd + tid];
    for (int cc = 0; cc < 8; ++cc) {
      stS[cc][tid] = m;
      m = aL * m + leS[cc][tid];
    }
  }
  __syncthreads();
  if (active) {
    float m = stS[c][o];
    for (int u = 0; u < 125; ++u) {
      m = a2 * m + oma2 * Rb[(size_t)(t0 + u) * OUTd + o];
      Ob[(size_t)(t0 + u) * OUTd + o] = m;
    }
  }
}

extern "C" void kernel_launch(void* const* d_in, const int* in_sizes, int n_in,
                              void* d_out, int out_size, void* d_ws, size_t ws_size,
                              hipStream_t stream) {
  const float* x      = (const float*)d_in[0];
  const float* W1     = (const float*)d_in[1];
  const float* b1     = (const float*)d_in[2];
  const float* tau_m1 = (const float*)d_in[3];
  const float* tau_n1 = (const float*)d_in[4];
  const float* W2     = (const float*)d_in[5];
  const float* b2     = (const float*)d_in[6];
  const float* tau_m2 = (const float*)d_in[7];
  const float* mem1_0 = (const float*)d_in[8];
  const float* mem2_0 = (const float*)d_in[9];
  float* out = (float*)d_out;

  // Workspace layout: proj (262.1 MB) | spike masks (8.2 MB) | R (10.2 MB)
  float* proj = (float*)d_ws;
  unsigned long long* spk =
      (unsigned long long*)((char*)d_ws + (size_t)Md * Hd * sizeof(float));
  float* R = (float*)((char*)spk + (size_t)Md * 8 * sizeof(unsigned long long));

  gemm1_kernel<<<dim3(Hd / 256, Md / 128), 256, 0, stream>>>(x, W1, b1, proj);
  scan1_kernel<<<dim3(Bd * Hd / 256), 256, 0, stream>>>(proj, tau_m1, tau_n1,
                                                        mem1_0, spk);
  gemm2_kernel<<<dim3((Md + 95) / 96), 256, 0, stream>>>(spk, W2, b2, R, Md);
  scan2_kernel<<<dim3(Bd), 256, 0, stream>>>(R, tau_m2, mem2_0, out);
}

// Round 3
// 2201.968 us; speedup vs baseline: 3.9733x; 3.9733x over previous
//
#include <hip/hip_runtime.h>
#include <stdint.h>

#define Bd   128
#define Td   1000
#define INd  700
#define Hd   512
#define OUTd 20
#define Md   (Bd * Td)

// ---------------------------------------------------------------------------
// GEMM1: proj[m][n] = sum_k X[m][k] * W1[n][k] + b1[n]
// Round-1 proven shape: 128x128 tile, BK=8, 256 threads, 8x8 micro-tile.
// Fixes vs round 1: (a) split-quad fragment reads (ty*4 / 64+ty*4) -> all
// LDS reads <=2-way (free), vs 4-way at stride 8; (b) double-buffered LDS,
// one barrier per K-iter; (c) grid n-fastest for X L2 reuse.
// acc[8][8]=64 VGPRs + 16 frag + 8 staging => ~105 VGPRs, no spill
// (round 2's 8x16 tile spilled: 19 GB scratch writes, VALUBusy 8%).
// Per-element ascending-k fmaf chain unchanged -> proj bit-identical to r1.
// ---------------------------------------------------------------------------
__global__ __launch_bounds__(256) void gemm1_kernel(
    const float* __restrict__ X, const float* __restrict__ W1,
    const float* __restrict__ b1, float* __restrict__ proj) {
  __shared__ __align__(16) float As[2][8][128];
  __shared__ __align__(16) float Bs[2][8][128];
  const int tid = threadIdx.x;
  const int n0 = blockIdx.x * 128;   // n fastest -> 4 n-blocks share X m-tile
  const int m0 = blockIdx.y * 128;
  const int tx = tid & 15;           // n quad group
  const int ty = tid >> 4;           // m quad group
  const int lrow = tid >> 1;         // 0..127
  const int lcol = (tid & 1) << 2;   // 0 or 4

  const float* Ap = X + (size_t)(m0 + lrow) * INd + lcol;
  const float* Bp = W1 + (size_t)(n0 + lrow) * INd + lcol;

  const float4 z4 = make_float4(0.f, 0.f, 0.f, 0.f);
  float4 av, bv;

  // prologue: tile 0 fully in-bounds
  av = *(const float4*)(Ap);
  bv = *(const float4*)(Bp);
  As[0][lcol + 0][lrow] = av.x; As[0][lcol + 1][lrow] = av.y;
  As[0][lcol + 2][lrow] = av.z; As[0][lcol + 3][lrow] = av.w;
  Bs[0][lcol + 0][lrow] = bv.x; Bs[0][lcol + 1][lrow] = bv.y;
  Bs[0][lcol + 2][lrow] = bv.z; Bs[0][lcol + 3][lrow] = bv.w;
  __syncthreads();

  float acc[8][8];
#pragma unroll
  for (int i = 0; i < 8; ++i)
#pragma unroll
    for (int j = 0; j < 8; ++j) acc[i][j] = 0.f;

  const int KITERS = (INd + 7) / 8;  // 88; last iter half-valid (700=87*8+4)
#pragma unroll 1
  for (int iter = 0; iter < KITERS; ++iter) {
    const int cur = iter & 1;
    const bool have_next = (iter + 1 < KITERS);
    if (have_next) {
      const int k0 = (iter + 1) * 8;
      const bool ok = (k0 + lcol + 4 <= INd);
      av = ok ? *(const float4*)(Ap + k0) : z4;
      bv = ok ? *(const float4*)(Bp + k0) : z4;
    }
#pragma unroll
    for (int k = 0; k < 8; ++k) {
      float a[8], b[8];
      *(float4*)&a[0] = *(const float4*)&As[cur][k][ty * 4];
      *(float4*)&a[4] = *(const float4*)&As[cur][k][64 + ty * 4];
      *(float4*)&b[0] = *(const float4*)&Bs[cur][k][tx * 4];
      *(float4*)&b[4] = *(const float4*)&Bs[cur][k][64 + tx * 4];
#pragma unroll
      for (int i = 0; i < 8; ++i)
#pragma unroll
        for (int j = 0; j < 8; ++j) acc[i][j] = fmaf(a[i], b[j], acc[i][j]);
    }
    if (have_next) {
      const int nxt = cur ^ 1;
      As[nxt][lcol + 0][lrow] = av.x; As[nxt][lcol + 1][lrow] = av.y;
      As[nxt][lcol + 2][lrow] = av.z; As[nxt][lcol + 3][lrow] = av.w;
      Bs[nxt][lcol + 0][lrow] = bv.x; Bs[nxt][lcol + 1][lrow] = bv.y;
      Bs[nxt][lcol + 2][lrow] = bv.z; Bs[nxt][lcol + 3][lrow] = bv.w;
      __syncthreads();
    }
  }

  const float4 bia0 = *(const float4*)&b1[n0 + tx * 4];
  const float4 bia1 = *(const float4*)&b1[n0 + 64 + tx * 4];

#pragma unroll
  for (int half = 0; half < 2; ++half)
#pragma unroll
    for (int i = 0; i < 4; ++i) {
      const int m = m0 + half * 64 + ty * 4 + i;
      float* row = proj + (size_t)m * Hd + n0;
      const int r = half * 4 + i;
      float4 v0, v1;
      v0.x = acc[r][0] + bia0.x; v0.y = acc[r][1] + bia0.y;
      v0.z = acc[r][2] + bia0.z; v0.w = acc[r][3] + bia0.w;
      v1.x = acc[r][4] + bia1.x; v1.y = acc[r][5] + bia1.y;
      v1.z = acc[r][6] + bia1.z; v1.w = acc[r][7] + bia1.w;
      *(float4*)(row + tx * 4) = v0;
      *(float4*)(row + 64 + tx * 4) = v1;
    }
}

// ---------------------------------------------------------------------------
// Scan1: per-(b,h) LIF + dendritic filter; emit spike bitmasks.
// 4-deep x 8-wide register prefetch ring (latency-bound at 1 wave/SIMD).
// ---------------------------------------------------------------------------
__global__ __launch_bounds__(256) void scan1_kernel(
    const float* __restrict__ proj, const float* __restrict__ tau_m1,
    const float* __restrict__ tau_n1, const float* __restrict__ mem1_0,
    unsigned long long* __restrict__ spk) {
  const int gid = blockIdx.x * 256 + threadIdx.x;   // 0..65535
  const int b = gid >> 9;
  const int h = gid & 511;
  const float am = 1.f / (1.f + expf(-tau_m1[h]));
  const float bn = 1.f / (1.f + expf(-tau_n1[h]));
  const float omam = 1.f - am, ombn = 1.f - bn;
  float mem = mem1_0[(b << 9) | h];
  float d = 0.f, s = 0.f;
  const float* pp = proj + (size_t)b * Td * Hd + h;
  unsigned long long* sp = spk + (size_t)b * Td * 8 + (h >> 6);
  const int lane = threadIdx.x & 63;

  float buf[4][8];
#pragma unroll
  for (int q = 0; q < 3; ++q)
#pragma unroll
    for (int u = 0; u < 8; ++u)
      buf[q][u] = pp[(size_t)(q * 8 + u) * Hd];

#pragma unroll 1
  for (int t0 = 0; t0 < Td; t0 += 8) {
    const int qc = (t0 >> 3) & 3;
    const int qn = (qc + 3) & 3;      // slot 3 steps ahead
    const int tp = t0 + 24;
#pragma unroll
    for (int u = 0; u < 8; ++u) {
      const int tt = (tp + u < Td) ? (tp + u) : (Td - 1);
      buf[qn][u] = pp[(size_t)tt * Hd];
    }
#pragma unroll
    for (int u = 0; u < 8; ++u) {
      const float p = buf[qc][u];
      d = bn * d + ombn * p;
      mem = am * mem + omam * d - s;
      const bool fire = mem > 1.0f;
      s = fire ? 1.f : 0.f;
      const unsigned long long msk = __ballot(fire);
      if (lane == 0) sp[(size_t)(t0 + u) * 8] = msk;
    }
  }
}

// ---------------------------------------------------------------------------
// GEMM2: R[m][o] = b2[o] + sum over set spike bits h of W2[o][h].
// ---------------------------------------------------------------------------
__global__ __launch_bounds__(256) void gemm2_kernel(
    const unsigned long long* __restrict__ spk, const float* __restrict__ W2,
    const float* __restrict__ b2, float* __restrict__ R, int Mtotal) {
  __shared__ float W2s[Hd * OUTd];
  const int tid = threadIdx.x;
  for (int idx = tid; idx < Hd * OUTd; idx += 256) {
    const int h = idx / OUTd, o = idx - h * OUTd;
    W2s[idx] = W2[o * Hd + h];
  }
  __syncthreads();
  const int wave = tid >> 6, lane = tid & 63;
  const int mg = lane / OUTd;            // 0..3 (3 = idle lane)
  const int o = lane - mg * OUTd;        // 0..19
  if (mg >= 3) return;                   // no barriers after this point
  const float bias = b2[o];
  const int mbase = blockIdx.x * 96 + wave * 24 + mg;
#pragma unroll 1
  for (int i = 0; i < 8; ++i) {
    const int m = mbase + i * 3;
    if (m >= Mtotal) break;
    float r = bias;
    const unsigned long long* mp = spk + (size_t)m * 8;
#pragma unroll
    for (int c = 0; c < 8; ++c) {
      unsigned long long mask = mp[c];
      const float* wrow = W2s + (c << 6) * OUTd + o;
      while (mask) {
        const int j = __builtin_ctzll(mask);
        mask &= mask - 1;
        r += wrow[j * OUTd];
      }
    }
    R[(size_t)m * OUTd + o] = r;
  }
}

// ---------------------------------------------------------------------------
// Scan2: per-(b,o) leaky readout, chunked parallel scan (8 x 125).
// ---------------------------------------------------------------------------
__global__ __launch_bounds__(256) void scan2_kernel(
    const float* __restrict__ R, const float* __restrict__ tau_m2,
    const float* __restrict__ mem2_0, float* __restrict__ out) {
  __shared__ float leS[8][20];
  __shared__ float stS[8][20];
  const int b = blockIdx.x;
  const int tid = threadIdx.x;
  const int c = tid / OUTd;          // chunk 0..7 (active if tid < 160)
  const int o = tid - c * OUTd;
  const bool active = tid < 160;
  float a2 = 0.f, oma2 = 0.f;
  if (active) {
    a2 = 1.f / (1.f + expf(-tau_m2[o]));
    oma2 = 1.f - a2;
  }
  const float* Rb = R + (size_t)b * Td * OUTd;
  float* Ob = out + (size_t)b * Td * OUTd;
  const int t0 = c * 125;

  if (active) {
    float m = 0.f;
    for (int u = 0; u < 125; ++u)
      m = a2 * m + oma2 * Rb[(size_t)(t0 + u) * OUTd + o];
    leS[c][o] = m;
  }
  __syncthreads();
  if (tid < OUTd) {
    const float a = 1.f / (1.f + expf(-tau_m2[tid]));
    float aL = 1.f;
    for (int i = 0; i < 125; ++i) aL *= a;
    float m = mem2_0[b * OUTd + tid];
    for (int cc = 0; cc < 8; ++cc) {
      stS[cc][tid] = m;
      m = aL * m + leS[cc][tid];
    }
  }
  __syncthreads();
  if (active) {
    float m = stS[c][o];
    for (int u = 0; u < 125; ++u) {
      m = a2 * m + oma2 * Rb[(size_t)(t0 + u) * OUTd + o];
      Ob[(size_t)(t0 + u) * OUTd + o] = m;
    }
  }
}

extern "C" void kernel_launch(void* const* d_in, const int* in_sizes, int n_in,
                              void* d_out, int out_size, void* d_ws, size_t ws_size,
                              hipStream_t stream) {
  const float* x      = (const float*)d_in[0];
  const float* W1     = (const float*)d_in[1];
  const float* b1     = (const float*)d_in[2];
  const float* tau_m1 = (const float*)d_in[3];
  const float* tau_n1 = (const float*)d_in[4];
  const float* W2     = (const float*)d_in[5];
  const float* b2     = (const float*)d_in[6];
  const float* tau_m2 = (const float*)d_in[7];
  const float* mem1_0 = (const float*)d_in[8];
  const float* mem2_0 = (const float*)d_in[9];
  float* out = (float*)d_out;

  // Workspace layout: proj (262.1 MB) | spike masks (8.2 MB) | R (10.2 MB)
  float* proj = (float*)d_ws;
  unsigned long long* spk =
      (unsigned long long*)((char*)d_ws + (size_t)Md * Hd * sizeof(float));
  float* R = (float*)((char*)spk + (size_t)Md * 8 * sizeof(unsigned long long));

  gemm1_kernel<<<dim3(Hd / 128, Md / 128), 256, 0, stream>>>(x, W1, b1, proj);
  scan1_kernel<<<dim3(Bd * Hd / 256), 256, 0, stream>>>(proj, tau_m1, tau_n1,
                                                        mem1_0, spk);
  gemm2_kernel<<<dim3((Md + 95) / 96), 256, 0, stream>>>(spk, W2, b2, R, Md);
  scan2_kernel<<<dim3(Bd), 256, 0, stream>>>(R, tau_m2, mem2_0, out);
}

// Round 4
// 1430.434 us; speedup vs baseline: 6.1163x; 1.5394x over previous
//
#include <hip/hip_runtime.h>
#include <stdint.h>

#define Bd   128
#define Td   1000
#define INd  700
#define Hd   512
#define OUTd 20
#define Md   (Bd * Td)
#define KPAD 704                 // 22 * 32
#define KIT  22

typedef _Float16 f16;
typedef f16 f16x4 __attribute__((ext_vector_type(4)));
typedef f16 f16x8 __attribute__((ext_vector_type(8)));
typedef float f32x4 __attribute__((ext_vector_type(4)));

// ---------------------------------------------------------------------------
// W1 presplit: W1 fp32 [512][700] -> W1a,W1b f16 [512][704] (zero-padded k).
// x = x1 + x2, x1 = fp16(x), x2 = fp16(x - x1): 22-bit effective mantissa.
// ---------------------------------------------------------------------------
__global__ __launch_bounds__(256) void w1split_kernel(
    const float* __restrict__ W1, f16* __restrict__ W1a,
    f16* __restrict__ W1b) {
  const int idx = blockIdx.x * 256 + threadIdx.x;
  if (idx >= 512 * KPAD) return;
  const int n = idx / KPAD, k = idx - n * KPAD;
  const float v = (k < INd) ? W1[n * INd + k] : 0.f;
  const f16 h1 = (f16)v;
  const f16 h2 = (f16)(v - (float)h1);
  W1a[idx] = h1;
  W1b[idx] = h2;
}

// ---------------------------------------------------------------------------
// GEMM1 via MFMA fp16 split-2: proj = X*W1^T + b1 as 3 mfma terms
// (x1w1 + x1w2 + x2w1), fp32 accumulate. 128x128 tile, BK=32, 256 threads,
// wave = 64x64 quadrant = 4x4 grid of 16x16x32 mfma tiles (48 mfma/iter).
// X split to fp16 pair on the fly during staging; W1 presplit.
// LDS rows padded to 40 halves -> frag ds_read_b128 is 2-way (free).
// Register prefetch of next tile's global loads issued before compute.
// ---------------------------------------------------------------------------
__global__ __launch_bounds__(256) void gemm1_kernel(
    const float* __restrict__ X, const f16* __restrict__ W1a,
    const f16* __restrict__ W1b, const float* __restrict__ b1,
    float* __restrict__ proj) {
  __shared__ __align__(16) f16 A1s[128 * 40];
  __shared__ __align__(16) f16 A2s[128 * 40];
  __shared__ __align__(16) f16 B1s[128 * 40];
  __shared__ __align__(16) f16 B2s[128 * 40];

  const int tid = threadIdx.x;
  const int n0 = blockIdx.x * 128;   // n fastest -> 4 n-blocks share X m-tile
  const int m0 = blockIdx.y * 128;

  // staging mapping: thread -> (row 0..127, k-halfrange 0 or 16)
  const int srow = tid >> 1;
  const int skq  = (tid & 1) << 4;

  const float* Xp  = X + (size_t)(m0 + srow) * INd;
  const f16*   Bap = W1a + (size_t)(n0 + srow) * KPAD + skq;
  const f16*   Bbp = W1b + (size_t)(n0 + srow) * KPAD + skq;

  // wave tiling: wave -> 64x64 quadrant; 4x4 of 16x16 mfma tiles
  const int wv = tid >> 6, lane = tid & 63;
  const int wm0 = (wv >> 1) * 64, wn0 = (wv & 1) * 64;
  const int fr = lane & 15;          // frag row (m for A, n for B, col for D)
  const int fq = lane >> 4;          // quad: k-offset fq*8 (A/B), row fq*4 (D)

  f32x4 acc[4][4];
#pragma unroll
  for (int i = 0; i < 4; ++i)
#pragma unroll
    for (int j = 0; j < 4; ++j) acc[i][j] = (f32x4){0.f, 0.f, 0.f, 0.f};

  const float4 z4 = make_float4(0.f, 0.f, 0.f, 0.f);
  float4 ax[4];
  f16x8 bq1[2], bq2[2];

  // prefetch tile 0 (k0 = 0: A fully valid)
#pragma unroll
  for (int i = 0; i < 4; ++i) ax[i] = *(const float4*)(Xp + skq + 4 * i);
  bq1[0] = *(const f16x8*)(Bap);     bq1[1] = *(const f16x8*)(Bap + 8);
  bq2[0] = *(const f16x8*)(Bbp);     bq2[1] = *(const f16x8*)(Bbp + 8);

#pragma unroll 1
  for (int it = 0; it < KIT; ++it) {
    __syncthreads();                 // previous compute's LDS reads done
    // ---- stage current tile into LDS (convert A fp32 -> fp16 pair) ----
#pragma unroll
    for (int i = 0; i < 4; ++i) {
      const float4 v = ax[i];
      f16x4 h1, h2;
      h1.x = (f16)v.x; h2.x = (f16)(v.x - (float)h1.x);
      h1.y = (f16)v.y; h2.y = (f16)(v.y - (float)h1.y);
      h1.z = (f16)v.z; h2.z = (f16)(v.z - (float)h1.z);
      h1.w = (f16)v.w; h2.w = (f16)(v.w - (float)h1.w);
      *(f16x4*)&A1s[srow * 40 + skq + 4 * i] = h1;
      *(f16x4*)&A2s[srow * 40 + skq + 4 * i] = h2;
    }
    *(f16x8*)&B1s[srow * 40 + skq]     = bq1[0];
    *(f16x8*)&B1s[srow * 40 + skq + 8] = bq1[1];
    *(f16x8*)&B2s[srow * 40 + skq]     = bq2[0];
    *(f16x8*)&B2s[srow * 40 + skq + 8] = bq2[1];
    __syncthreads();
    // ---- prefetch next tile (loads in flight during compute) ----
    if (it + 1 < KIT) {
      const int k0 = (it + 1) * 32;
#pragma unroll
      for (int i = 0; i < 4; ++i) {
        const int k = k0 + skq + 4 * i;
        ax[i] = (k + 4 <= INd) ? *(const float4*)(Xp + k) : z4;
      }
      bq1[0] = *(const f16x8*)(Bap + k0);
      bq1[1] = *(const f16x8*)(Bap + k0 + 8);
      bq2[0] = *(const f16x8*)(Bbp + k0);
      bq2[1] = *(const f16x8*)(Bbp + k0 + 8);
    }
    // ---- compute: 16 ds_read_b128 + 48 mfma ----
    f16x8 a1f[4], a2f[4], b1f[4], b2f[4];
#pragma unroll
    for (int mi = 0; mi < 4; ++mi) {
      const int off = (wm0 + mi * 16 + fr) * 40 + fq * 8;
      a1f[mi] = *(const f16x8*)&A1s[off];
      a2f[mi] = *(const f16x8*)&A2s[off];
    }
#pragma unroll
    for (int ni = 0; ni < 4; ++ni) {
      const int off = (wn0 + ni * 16 + fr) * 40 + fq * 8;
      b1f[ni] = *(const f16x8*)&B1s[off];
      b2f[ni] = *(const f16x8*)&B2s[off];
    }
#pragma unroll
    for (int mi = 0; mi < 4; ++mi)
#pragma unroll
      for (int ni = 0; ni < 4; ++ni) {
        acc[mi][ni] = __builtin_amdgcn_mfma_f32_16x16x32_f16(
            a1f[mi], b1f[ni], acc[mi][ni], 0, 0, 0);
        acc[mi][ni] = __builtin_amdgcn_mfma_f32_16x16x32_f16(
            a1f[mi], b2f[ni], acc[mi][ni], 0, 0, 0);
        acc[mi][ni] = __builtin_amdgcn_mfma_f32_16x16x32_f16(
            a2f[mi], b1f[ni], acc[mi][ni], 0, 0, 0);
      }
  }

  // ---- epilogue: D[row=fq*4+r][col=fr] per 16x16 tile, + bias ----
#pragma unroll
  for (int ni = 0; ni < 4; ++ni) {
    const int n = n0 + wn0 + ni * 16 + fr;
    const float bias = b1[n];
#pragma unroll
    for (int mi = 0; mi < 4; ++mi) {
      const int mb = m0 + wm0 + mi * 16 + fq * 4;
      float* p = proj + (size_t)mb * Hd + n;
#pragma unroll
      for (int r = 0; r < 4; ++r)
        p[(size_t)r * Hd] = acc[mi][ni][r] + bias;
    }
  }
}

// ---------------------------------------------------------------------------
// Scan1: per-(b,h) LIF + dendritic filter; emit spike bitmasks.
// 4-deep x 8-wide register prefetch ring (latency-bound at 1 wave/SIMD).
// ---------------------------------------------------------------------------
__global__ __launch_bounds__(256) void scan1_kernel(
    const float* __restrict__ proj, const float* __restrict__ tau_m1,
    const float* __restrict__ tau_n1, const float* __restrict__ mem1_0,
    unsigned long long* __restrict__ spk) {
  const int gid = blockIdx.x * 256 + threadIdx.x;   // 0..65535
  const int b = gid >> 9;
  const int h = gid & 511;
  const float am = 1.f / (1.f + expf(-tau_m1[h]));
  const float bn = 1.f / (1.f + expf(-tau_n1[h]));
  const float omam = 1.f - am, ombn = 1.f - bn;
  float mem = mem1_0[(b << 9) | h];
  float d = 0.f, s = 0.f;
  const float* pp = proj + (size_t)b * Td * Hd + h;
  unsigned long long* sp = spk + (size_t)b * Td * 8 + (h >> 6);
  const int lane = threadIdx.x & 63;

  float buf[4][8];
#pragma unroll
  for (int q = 0; q < 3; ++q)
#pragma unroll
    for (int u = 0; u < 8; ++u)
      buf[q][u] = pp[(size_t)(q * 8 + u) * Hd];

#pragma unroll 1
  for (int t0 = 0; t0 < Td; t0 += 8) {
    const int qc = (t0 >> 3) & 3;
    const int qn = (qc + 3) & 3;      // slot 3 steps ahead
    const int tp = t0 + 24;
#pragma unroll
    for (int u = 0; u < 8; ++u) {
      const int tt = (tp + u < Td) ? (tp + u) : (Td - 1);
      buf[qn][u] = pp[(size_t)tt * Hd];
    }
#pragma unroll
    for (int u = 0; u < 8; ++u) {
      const float p = buf[qc][u];
      d = bn * d + ombn * p;
      mem = am * mem + omam * d - s;
      const bool fire = mem > 1.0f;
      s = fire ? 1.f : 0.f;
      const unsigned long long msk = __ballot(fire);
      if (lane == 0) sp[(size_t)(t0 + u) * 8] = msk;
    }
  }
}

// ---------------------------------------------------------------------------
// GEMM2: R[m][o] = b2[o] + sum over set spike bits h of W2[o][h].
// ---------------------------------------------------------------------------
__global__ __launch_bounds__(256) void gemm2_kernel(
    const unsigned long long* __restrict__ spk, const float* __restrict__ W2,
    const float* __restrict__ b2, float* __restrict__ R, int Mtotal) {
  __shared__ float W2s[Hd * OUTd];
  const int tid = threadIdx.x;
  for (int idx = tid; idx < Hd * OUTd; idx += 256) {
    const int h = idx / OUTd, o = idx - h * OUTd;
    W2s[idx] = W2[o * Hd + h];
  }
  __syncthreads();
  const int wave = tid >> 6, lane = tid & 63;
  const int mg = lane / OUTd;            // 0..3 (3 = idle lane)
  const int o = lane - mg * OUTd;        // 0..19
  if (mg >= 3) return;                   // no barriers after this point
  const float bias = b2[o];
  const int mbase = blockIdx.x * 96 + wave * 24 + mg;
#pragma unroll 1
  for (int i = 0; i < 8; ++i) {
    const int m = mbase + i * 3;
    if (m >= Mtotal) break;
    float r = bias;
    const unsigned long long* mp = spk + (size_t)m * 8;
#pragma unroll
    for (int c = 0; c < 8; ++c) {
      unsigned long long mask = mp[c];
      const float* wrow = W2s + (c << 6) * OUTd + o;
      while (mask) {
        const int j = __builtin_ctzll(mask);
        mask &= mask - 1;
        r += wrow[j * OUTd];
      }
    }
    R[(size_t)m * OUTd + o] = r;
  }
}

// ---------------------------------------------------------------------------
// Scan2: per-(b,o) leaky readout, chunked parallel scan (8 x 125).
// ---------------------------------------------------------------------------
__global__ __launch_bounds__(256) void scan2_kernel(
    const float* __restrict__ R, const float* __restrict__ tau_m2,
    const float* __restrict__ mem2_0, float* __restrict__ out) {
  __shared__ float leS[8][20];
  __shared__ float stS[8][20];
  const int b = blockIdx.x;
  const int tid = threadIdx.x;
  const int c = tid / OUTd;          // chunk 0..7 (active if tid < 160)
  const int o = tid - c * OUTd;
  const bool active = tid < 160;
  float a2 = 0.f, oma2 = 0.f;
  if (active) {
    a2 = 1.f / (1.f + expf(-tau_m2[o]));
    oma2 = 1.f - a2;
  }
  const float* Rb = R + (size_t)b * Td * OUTd;
  float* Ob = out + (size_t)b * Td * OUTd;
  const int t0 = c * 125;

  if (active) {
    float m = 0.f;
    for (int u = 0; u < 125; ++u)
      m = a2 * m + oma2 * Rb[(size_t)(t0 + u) * OUTd + o];
    leS[c][o] = m;
  }
  __syncthreads();
  if (tid < OUTd) {
    const float a = 1.f / (1.f + expf(-tau_m2[tid]));
    float aL = 1.f;
    for (int i = 0; i < 125; ++i) aL *= a;
    float m = mem2_0[b * OUTd + tid];
    for (int cc = 0; cc < 8; ++cc) {
      stS[cc][tid] = m;
      m = aL * m + leS[cc][tid];
    }
  }
  __syncthreads();
  if (active) {
    float m = stS[c][o];
    for (int u = 0; u < 125; ++u) {
      m = a2 * m + oma2 * Rb[(size_t)(t0 + u) * OUTd + o];
      Ob[(size_t)(t0 + u) * OUTd + o] = m;
    }
  }
}

extern "C" void kernel_launch(void* const* d_in, const int* in_sizes, int n_in,
                              void* d_out, int out_size, void* d_ws, size_t ws_size,
                              hipStream_t stream) {
  const float* x      = (const float*)d_in[0];
  const float* W1     = (const float*)d_in[1];
  const float* b1     = (const float*)d_in[2];
  const float* tau_m1 = (const float*)d_in[3];
  const float* tau_n1 = (const float*)d_in[4];
  const float* W2     = (const float*)d_in[5];
  const float* b2     = (const float*)d_in[6];
  const float* tau_m2 = (const float*)d_in[7];
  const float* mem1_0 = (const float*)d_in[8];
  const float* mem2_0 = (const float*)d_in[9];
  float* out = (float*)d_out;

  // Workspace: proj (262.1 MB) | spk (8.2 MB) | R (10.2 MB).
  // W1 fp16 splits live inside the R region (1.44 MB <= 10.2 MB): needed
  // only during gemm1, and gemm2 overwrites R afterwards.
  float* proj = (float*)d_ws;
  unsigned long long* spk =
      (unsigned long long*)((char*)d_ws + (size_t)Md * Hd * sizeof(float));
  float* R = (float*)((char*)spk + (size_t)Md * 8 * sizeof(unsigned long long));
  f16* W1a = (f16*)R;
  f16* W1b = W1a + 512 * KPAD;

  w1split_kernel<<<dim3((512 * KPAD + 255) / 256), 256, 0, stream>>>(W1, W1a,
                                                                     W1b);
  gemm1_kernel<<<dim3(Hd / 128, Md / 128), 256, 0, stream>>>(x, W1a, W1b, b1,
                                                             proj);
  scan1_kernel<<<dim3(Bd * Hd / 256), 256, 0, stream>>>(proj, tau_m1, tau_n1,
                                                        mem1_0, spk);
  gemm2_kernel<<<dim3((Md + 95) / 96), 256, 0, stream>>>(spk, W2, b2, R, Md);
  scan2_kernel<<<dim3(Bd), 256, 0, stream>>>(R, tau_m2, mem2_0, out);
}